// Round 13
// baseline (344.762 us; speedup 1.0000x reference)
//
#include <hip/hip_runtime.h>
#include <hip/hip_bf16.h>
#include <cstddef>

// Fused 3-layer LSTM, wavefront-pipelined, swapped-operand MFMA, 16 waves.
// R13: NO ORPHAN — per-layer tile 12 folded into a regular wave as an extra
// q (guard kg<2 on that q only). Equalized chains:
//   L0: 4 waves NT=4,3,3,3 (tiles 0-3 | 4-6+x-stage | 7-9 | 10-12)
//   L1: 6 waves NT=3,2,2,2,2,2 (0-2 | 3-4 | 5-6 | 7-8 | 9-10 | 11-12)
//   L2: 6 waves, same tiling.
// Skews: L0@it, L1@it-1, L2@it-2. ONE s_barrier per iter. DUAL acc chains.
// 8-trans fused cell update (sigma*tanh sharing one rcp).
//
// Regions (granule = 8k x 16b = 128 shorts; lane-linear frag reads):
//   H0[2], H1[3], H2[2]; buf = 9 granules: g0 = x (L0 only); g1..7 = h units
//   (unit u -> g 1+(u>>3), pos u&7); bias act==1.0 at g7p2 (slot 50); g8 pad.
// Schedule: h0(t)->H0[(t+1)&1]; x(t+1) staged into same buf g0;
//   h1(t)->H1[t%3]; h2(t)->H2[t&1]. (Same verified map as R11.)

#define T_STEPS 256
#define NITER   258
#define BTOT    4096
#define NTHR    1024
#define GS      128
#define BUFSZ   (9 * GS)

typedef __attribute__((ext_vector_type(8))) short short8;
typedef __attribute__((ext_vector_type(4))) float f32x4;

#define BAR() do { \
    asm volatile("s_waitcnt lgkmcnt(0)" ::: "memory"); \
    __builtin_amdgcn_sched_barrier(0); \
    __builtin_amdgcn_s_barrier(); \
    __builtin_amdgcn_sched_barrier(0); \
} while (0)

__device__ __forceinline__ unsigned short f2bf(float x) {     // RNE
    union { __hip_bfloat16 b; unsigned short s; } u;
    u.b = __float2bfloat16(x);
    return u.s;
}
__device__ __forceinline__ float bf2f(unsigned short s) {
    union { unsigned u; float f; } v; v.u = (unsigned)s << 16; return v.f;
}

// 8-trans cell update: sigma(i)tanh(g) = (e2g-1)*rcp((1+e_i)(1+e2g));
// sigma(o)tanh(c) likewise. Clamps keep e2g/e2c finite (no inf/inf NaN).
__device__ __forceinline__ float cell_upd(f32x4 g, float& cst) {
    const float K1 = 1.4426950408889634f;   // log2(e)
    const float K2 = 2.8853900817779268f;   // 2*log2(e)
    float gc  = fminf(fmaxf(g[2], -30.0f), 30.0f);
    float eg  = __builtin_amdgcn_exp2f(K2 * gc);
    float ei  = __builtin_amdgcn_exp2f(-K1 * g[0]);
    float itg = (eg - 1.0f) * __builtin_amdgcn_rcpf((1.0f + ei) * (1.0f + eg));
    float ef  = __builtin_amdgcn_exp2f(-K1 * g[1]);
    float fg  = __builtin_amdgcn_rcpf(1.0f + ef);
    float c   = fmaf(fg, cst, itg);
    cst = c;
    float cc  = fminf(fmaxf(c, -30.0f), 30.0f);
    float ec  = __builtin_amdgcn_exp2f(K2 * cc);
    float eo  = __builtin_amdgcn_exp2f(-K1 * g[3]);
    return (ec - 1.0f) * __builtin_amdgcn_rcpf((1.0f + eo) * (1.0f + ec));
}

// Weights -> (hi,lo) frags. Row N' = (T0+q)*16 + (lane&15), k = ks*32+kg*8+e.
// L0M: [w_ih(8)@k0-7 | w_hh@k8-57 | bias@58]; MID: [w_ih@k0-49 | bias@50 |
// zeros | w_hh@k64-113 | zeros].
template<bool L0M, int NT, int KS>
__device__ __forceinline__ void load_wb(int T0, int lane,
    const float* __restrict__ w_ih, const float* __restrict__ w_hh,
    const float* __restrict__ b_ih, const float* __restrict__ b_hh,
    short8 (&Wh)[NT][KS], short8 (&Wl)[NT][KS])
{
    const int m = lane & 15, kg = lane >> 4;
    #pragma unroll
    for (int q = 0; q < NT; ++q) {
        int gp = (T0 + q) * 16 + m;
        int gr = (gp < 200) ? ((gp & 3) * 50 + (gp >> 2)) : -1;
        float bias = (gr >= 0) ? (b_ih[gr] + b_hh[gr]) : 0.0f;
        #pragma unroll
        for (int ks = 0; ks < KS; ++ks)
            #pragma unroll
            for (int e = 0; e < 8; ++e) {
                int k = ks * 32 + kg * 8 + e;
                float v = 0.0f;
                if (gr >= 0) {
                    if (L0M) {
                        if (k < 8) v = w_ih[gr * 8 + k];
                        else if (k < 58) v = w_hh[gr * 50 + (k - 8)];
                        else if (k == 58) v = bias;
                    } else {
                        if (k < 50) v = w_ih[gr * 50 + k];
                        else if (k == 50) v = bias;
                        else if (k >= 64 && k < 114) v = w_hh[gr * 50 + (k - 64)];
                    }
                }
                unsigned short hb = f2bf(v);
                Wh[q][ks][e] = (short)hb;
                Wl[q][ks][e] = (short)f2bf(v - bf2f(hb));
            }
    }
}

// L0 wave: NT tiles, skew 0. Reads H0[it&1] (x@g0-0..7k + h@g1-7), writes
// h -> H0[(it+1)&1]. XST: stage x(it+1) -> H0[(it+1)&1].g0 after compute.
template<int T0, int NT, bool XST>
__device__ void role_l0(int lane, int b0, const float* __restrict__ xf,
    const float* w_ih, const float* w_hh, const float* b_ih, const float* b_hh,
    short (*H0)[BUFSZ])
{
    short8 Wh[NT][2], Wl[NT][2];
    load_wb<true, NT, 2>(T0, lane, w_ih, w_hh, b_ih, b_hh, Wh, Wl);
    float cst[NT];
    #pragma unroll
    for (int q = 0; q < NT; ++q) cst[q] = 0.0f;
    const int b = lane & 15, kg = lane >> 4;

    for (int it = 0; it < NITER; ++it) {
        const bool stg = XST && (kg == 0) && (it + 1 < T_STEPS);
        float xs[8];
        if (stg) {
            const float* xr = &xf[((size_t)(b0 + b) * T_STEPS + (it + 1)) * 8];
            *(float4*)&xs[0] = *(const float4*)xr;
            *(float4*)&xs[4] = *(const float4*)(xr + 4);
        }
        if (it < T_STEPS) {
            const short* rb = H0[it & 1];
            short*       wb = H0[(it + 1) & 1];
            short8 A0 = *(const short8*)&rb[kg * GS + b * 8];
            short8 A1 = *(const short8*)&rb[(4 + kg) * GS + b * 8];
            f32x4 accA[NT], accB[NT];
            #pragma unroll
            for (int q = 0; q < NT; ++q) {
                accA[q] = (f32x4){0.0f, 0.0f, 0.0f, 0.0f};
                accB[q] = (f32x4){0.0f, 0.0f, 0.0f, 0.0f};
            }
            #pragma unroll
            for (int q = 0; q < NT; ++q)
                accA[q] = __builtin_amdgcn_mfma_f32_16x16x32_bf16(Wh[q][0], A0, accA[q], 0, 0, 0);
            #pragma unroll
            for (int q = 0; q < NT; ++q)
                accA[q] = __builtin_amdgcn_mfma_f32_16x16x32_bf16(Wh[q][1], A1, accA[q], 0, 0, 0);
            #pragma unroll
            for (int q = 0; q < NT; ++q)
                accB[q] = __builtin_amdgcn_mfma_f32_16x16x32_bf16(Wl[q][0], A0, accB[q], 0, 0, 0);
            #pragma unroll
            for (int q = 0; q < NT; ++q)
                accB[q] = __builtin_amdgcn_mfma_f32_16x16x32_bf16(Wl[q][1], A1, accB[q], 0, 0, 0);
            #pragma unroll
            for (int q = 0; q < NT; ++q) {
                if ((T0 + q) < 12 || kg < 2) {          // tile-12 guard only
                    int u = (T0 + q) * 4 + kg;
                    float h = cell_upd(accA[q] + accB[q], cst[q]);
                    wb[(1 + (u >> 3)) * GS + b * 8 + (u & 7)] = (short)f2bf(h);
                }
            }
        }
        if (stg) {
            short8 hi;
            #pragma unroll
            for (int e = 0; e < 8; ++e) hi[e] = (short)f2bf(xs[e]);
            *(short8*)&H0[(it + 1) & 1][b * 8] = hi;
        }
        BAR();
    }
}

// Mid wave, NT tiles. LASTL: L2 (skew 2, hf at t=255); else L1 (skew 1).
// L1: x-side H0[it&1] (+1 granule gather), h-side H1[(it-2)%3], write H1[(it-1)%3].
// L2: x-side H1[(it-2)%3], h-side H2[(it+1)&1], write H2[it&1].
template<int T0, int NT, bool LASTL>
__device__ void role_mid(int lane,
    const float* w_ih, const float* w_hh, const float* b_ih, const float* b_hh,
    short (*H0)[BUFSZ], short (*H1)[BUFSZ], short (*H2)[BUFSZ], float* hfp)
{
    constexpr int SKEW = LASTL ? 2 : 1;
    short8 Wh[NT][4], Wl[NT][4];
    load_wb<false, NT, 4>(T0, lane, w_ih, w_hh, b_ih, b_hh, Wh, Wl);
    float cst[NT];
    #pragma unroll
    for (int q = 0; q < NT; ++q) cst[q] = 0.0f;
    const int b = lane & 15, kg = lane >> 4;
    int m0 = 0, m1 = 2, m2 = 1;      // it%3, (it-1)%3, (it-2)%3

    for (int it = 0; it < NITER; ++it) {
        int t = it - SKEW;
        if ((unsigned)t < T_STEPS) {
            const short* xsb = LASTL ? H1[m2] : H0[it & 1];
            const short* hsb = LASTL ? H2[(it + 1) & 1] : H1[m2];
            short*       wb  = LASTL ? H2[it & 1]       : H1[m1];

            short8 Ap[4];
            Ap[0] = *(const short8*)&xsb[(1 + kg) * GS + b * 8];
            Ap[1] = *(const short8*)&xsb[(5 + kg) * GS + b * 8];
            Ap[2] = *(const short8*)&hsb[(1 + kg) * GS + b * 8];
            Ap[3] = *(const short8*)&hsb[(5 + kg) * GS + b * 8];

            f32x4 accA[NT], accB[NT];
            #pragma unroll
            for (int q = 0; q < NT; ++q) {
                accA[q] = (f32x4){0.0f, 0.0f, 0.0f, 0.0f};
                accB[q] = (f32x4){0.0f, 0.0f, 0.0f, 0.0f};
            }
            #pragma unroll
            for (int ks = 0; ks < 4; ++ks)
                #pragma unroll
                for (int q = 0; q < NT; ++q)
                    accA[q] = __builtin_amdgcn_mfma_f32_16x16x32_bf16(Wh[q][ks], Ap[ks], accA[q], 0, 0, 0);
            #pragma unroll
            for (int ks = 0; ks < 4; ++ks)
                #pragma unroll
                for (int q = 0; q < NT; ++q)
                    accB[q] = __builtin_amdgcn_mfma_f32_16x16x32_bf16(Wl[q][ks], Ap[ks], accB[q], 0, 0, 0);

            #pragma unroll
            for (int q = 0; q < NT; ++q) {
                if ((T0 + q) < 12 || kg < 2) {          // tile-12 guard only
                    int u = (T0 + q) * 4 + kg;
                    float h = cell_upd(accA[q] + accB[q], cst[q]);
                    wb[(1 + (u >> 3)) * GS + b * 8 + (u & 7)] = (short)f2bf(h);
                    if (LASTL && t == T_STEPS - 1) hfp[b * 56 + u] = h;
                }
            }
        }
        BAR();
        int tmp = m2; m2 = m1; m1 = m0; m0 = tmp;
    }
}

__global__ __launch_bounds__(NTHR) void lstm_fused(
    const float* __restrict__ xf,
    const float* w_ih0, const float* w_hh0, const float* b_ih0, const float* b_hh0,
    const float* w_ih1, const float* w_hh1, const float* b_ih1, const float* b_hh1,
    const float* w_ih2, const float* w_hh2, const float* b_ih2, const float* b_hh2,
    const float* __restrict__ w_fc, const float* __restrict__ b_fc,
    float* __restrict__ out)
{
    __shared__ __align__(16) short H0[2][BUFSZ];
    __shared__ __align__(16) short H1[3][BUFSZ];
    __shared__ __align__(16) short H2[2][BUFSZ];
    __shared__ __align__(16) float hf[16 * 56];

    const int tid  = threadIdx.x;
    const int lane = tid & 63;
    const int wid  = tid >> 6;
    const int b0   = blockIdx.x * 16;

    for (int i = tid; i < 2 * BUFSZ; i += NTHR) { ((short*)H0)[i] = 0; ((short*)H2)[i] = 0; }
    for (int i = tid; i < 3 * BUFSZ; i += NTHR) ((short*)H1)[i] = 0;
    __syncthreads();

    // bias act columns (g7 p2 = slot 50) = 1.0 in all 7 buffers
    if (tid < 112) {
        int bufi = tid >> 4, b = tid & 15;
        short* bp = (bufi < 2) ? H0[bufi]
                  : (bufi < 5) ? H1[bufi - 2] : H2[bufi - 5];
        bp[7 * GS + b * 8 + 2] = (short)0x3F80;
    }
    // x(0) -> H0[0].g0
    if (tid < 16) {
        int b = tid;
        #pragma unroll
        for (int j = 0; j < 8; ++j) {
            float v = xf[((size_t)(b0 + b) * T_STEPS + 0) * 8 + j];
            H0[0][b * 8 + j] = (short)f2bf(v);
        }
    }
    __syncthreads();

    // 16 waves, no orphan; roles mixed across SIMDs (wid&3).
    if      (wid == 0)  role_l0<0, 4, false>(lane, b0, xf, w_ih0, w_hh0, b_ih0, b_hh0, H0);
    else if (wid == 1)  role_l0<4, 3, true >(lane, b0, xf, w_ih0, w_hh0, b_ih0, b_hh0, H0);
    else if (wid == 2)  role_l0<7, 3, false>(lane, b0, xf, w_ih0, w_hh0, b_ih0, b_hh0, H0);
    else if (wid == 3)  role_l0<10, 3, false>(lane, b0, xf, w_ih0, w_hh0, b_ih0, b_hh0, H0);
    else if (wid == 4)  role_mid<0,  3, false>(lane, w_ih1, w_hh1, b_ih1, b_hh1, H0, H1, H2, nullptr);
    else if (wid == 5)  role_mid<3,  2, false>(lane, w_ih1, w_hh1, b_ih1, b_hh1, H0, H1, H2, nullptr);
    else if (wid == 6)  role_mid<5,  2, false>(lane, w_ih1, w_hh1, b_ih1, b_hh1, H0, H1, H2, nullptr);
    else if (wid == 7)  role_mid<7,  2, false>(lane, w_ih1, w_hh1, b_ih1, b_hh1, H0, H1, H2, nullptr);
    else if (wid == 8)  role_mid<9,  2, false>(lane, w_ih1, w_hh1, b_ih1, b_hh1, H0, H1, H2, nullptr);
    else if (wid == 9)  role_mid<11, 2, false>(lane, w_ih1, w_hh1, b_ih1, b_hh1, H0, H1, H2, nullptr);
    else if (wid == 10) role_mid<0,  3, true >(lane, w_ih2, w_hh2, b_ih2, b_hh2, H0, H1, H2, hf);
    else if (wid == 11) role_mid<3,  2, true >(lane, w_ih2, w_hh2, b_ih2, b_hh2, H0, H1, H2, hf);
    else if (wid == 12) role_mid<5,  2, true >(lane, w_ih2, w_hh2, b_ih2, b_hh2, H0, H1, H2, hf);
    else if (wid == 13) role_mid<7,  2, true >(lane, w_ih2, w_hh2, b_ih2, b_hh2, H0, H1, H2, hf);
    else if (wid == 14) role_mid<9,  2, true >(lane, w_ih2, w_hh2, b_ih2, b_hh2, H0, H1, H2, hf);
    else                role_mid<11, 2, true >(lane, w_ih2, w_hh2, b_ih2, b_hh2, H0, H1, H2, hf);

    __syncthreads();

    if (tid < 96) {
        int b = tid / 6, o = tid - b * 6;
        float a = b_fc[o];
        #pragma unroll
        for (int n = 0; n < 50; ++n)
            a = fmaf(w_fc[o * 50 + n], hf[b * 56 + n], a);
        out[(size_t)(b0 + b) * 6 + o] = a;
    }
}

extern "C" void kernel_launch(void* const* d_in, const int* in_sizes, int n_in,
                              void* d_out, int out_size, void* d_ws, size_t ws_size,
                              hipStream_t stream) {
    (void)in_sizes; (void)n_in; (void)d_ws; (void)ws_size; (void)out_size;

    const float* x     = (const float*)d_in[0];
    const float* w_ih0 = (const float*)d_in[1];
    const float* w_hh0 = (const float*)d_in[2];
    const float* b_ih0 = (const float*)d_in[3];
    const float* b_hh0 = (const float*)d_in[4];
    const float* w_ih1 = (const float*)d_in[5];
    const float* w_hh1 = (const float*)d_in[6];
    const float* b_ih1 = (const float*)d_in[7];
    const float* b_hh1 = (const float*)d_in[8];
    const float* w_ih2 = (const float*)d_in[9];
    const float* w_hh2 = (const float*)d_in[10];
    const float* b_ih2 = (const float*)d_in[11];
    const float* b_hh2 = (const float*)d_in[12];
    const float* w_fc  = (const float*)d_in[13];
    const float* b_fc  = (const float*)d_in[14];
    float* out = (float*)d_out;

    lstm_fused<<<dim3(BTOT / 16), dim3(NTHR), 0, stream>>>(
        x, w_ih0, w_hh0, b_ih0, b_hh0, w_ih1, w_hh1, b_ih1, b_hh1,
        w_ih2, w_hh2, b_ih2, b_hh2, w_fc, b_fc, out);
}

// Round 14
// 303.527 us; speedup vs baseline: 1.1359x; 1.1359x over previous
//
#include <hip/hip_runtime.h>
#include <hip/hip_bf16.h>
#include <cstddef>

// R14 = R9 (best, 305us) + two update-cost cuts, structure untouched:
//  (1) gate scaling folded into weights/bias at load: rows i,f,o scaled by
//      -log2(e), row g by +2*log2(e) -> MFMA outputs are exp2 args directly.
//  (2) 8-trans cell update: sigma(i)tanh(g) and sigma(o)tanh(c) each share
//      one rcp. Exact algebra; clamps keep tanh-side exp2 finite (inf only
//      in denominators -> rcp -> 0 -> correct limit).
// Structure (R9): 12 waves, 768 thr, roles w0-2 L0 {0-4},{5-8},{9-12}(+x),
// w3-6 L1 NT=3, w7-10 L2 NT=3, w11 dual-orphan (L1+L2 tile12).
// Skew: L0@it, L1@it-1, L2@it-2. ONE s_barrier/iter. 2-term weight split,
// acts RNE bf16. Act LDS fragment-major: addr(k,b)=(k>>3)*128+b*8+(k&7).
// Bias rides act==1.0 column: L0 k=58, L1/L2 k=100.

#define T_STEPS 256
#define BTOT    4096
#define NTHR    768

typedef __attribute__((ext_vector_type(8))) short short8;
typedef __attribute__((ext_vector_type(4))) float f32x4;

#define BAR() do { \
    asm volatile("s_waitcnt lgkmcnt(0)" ::: "memory"); \
    __builtin_amdgcn_sched_barrier(0); \
    __builtin_amdgcn_s_barrier(); \
    __builtin_amdgcn_sched_barrier(0); \
} while (0)

__device__ __forceinline__ unsigned short f2bf(float x) {     // RNE
    union { __hip_bfloat16 b; unsigned short s; } u;
    u.b = __float2bfloat16(x);
    return u.s;
}
__device__ __forceinline__ float bf2f(unsigned short s) {
    union { unsigned u; float f; } v; v.u = (unsigned)s << 16; return v.f;
}

// Pre-scaled 8-trans cell update. Inputs (from scaled-weight MFMA):
//   g[0] = -K1*i_pre, g[1] = -K1*f_pre, g[2] = K2*g_pre, g[3] = -K1*o_pre.
// ei=e^-i etc. come from a bare exp2. Clamps only where the exp2 result
// must stay finite in a NUMERATOR (eg, ec).
__device__ __forceinline__ float cell_upd(f32x4 g, float& cst) {
    const float K2 = 2.8853900817779268f;   // 2*log2(e)
    float eg  = __builtin_amdgcn_exp2f(fminf(fmaxf(g[2], -126.0f), 126.0f));
    float ei  = __builtin_amdgcn_exp2f(g[0]);
    float ef  = __builtin_amdgcn_exp2f(g[1]);
    float eo  = __builtin_amdgcn_exp2f(g[3]);
    float itg = (eg - 1.0f) * __builtin_amdgcn_rcpf((1.0f + ei) * (1.0f + eg));
    float fg  = __builtin_amdgcn_rcpf(1.0f + ef);
    float c   = fmaf(fg, cst, itg);
    cst = c;
    float ec  = __builtin_amdgcn_exp2f(fminf(fmaxf(K2 * c, -126.0f), 126.0f));
    return (ec - 1.0f) * __builtin_amdgcn_rcpf((1.0f + eo) * (1.0f + ec));
}

// Weights -> (hi,lo) frags, PRE-SCALED per gate row: rows with (gp&3)==2
// (the tanh gate) by +K2, others by -K1. Bias (ridden on the act==1.0
// column) scales identically. K-packed [w_ih(XK) | w_hh(50) | bias@BIASK].
// Row N' = (T0+q)*16 + (lane&15), k = ks*32 + (lane>>4)*8 + e.
template<int NT, int KS, int XK, int BIASK>
__device__ __forceinline__ void load_wb(int T0, int lane,
    const float* __restrict__ w_ih, const float* __restrict__ w_hh,
    const float* __restrict__ b_ih, const float* __restrict__ b_hh,
    short8 (&Wh)[NT][KS], short8 (&Wl)[NT][KS])
{
    const float K1 = 1.4426950408889634f, K2 = 2.8853900817779268f;
    const int m = lane & 15, kg = lane >> 4;
    #pragma unroll
    for (int q = 0; q < NT; ++q) {
        int gp = (T0 + q) * 16 + m;
        int gr = (gp < 200) ? ((gp & 3) * 50 + (gp >> 2)) : -1;
        float scale = ((gp & 3) == 2) ? K2 : -K1;
        #pragma unroll
        for (int ks = 0; ks < KS; ++ks)
            #pragma unroll
            for (int e = 0; e < 8; ++e) {
                int k = ks * 32 + kg * 8 + e;
                float v = 0.0f;
                if (gr >= 0) {
                    if (k < XK) v = w_ih[gr * XK + k];
                    else if (k < XK + 50) v = w_hh[gr * 50 + (k - XK)];
                    else if (k == BIASK) v = b_ih[gr] + b_hh[gr];
                }
                v *= scale;
                unsigned short hb = f2bf(v);
                Wh[q][ks][e] = (short)hb;
                Wl[q][ks][e] = (short)f2bf(v - bf2f(hb));
            }
    }
}

// One layer-step: read ALL A-frags upfront (batched ds_reads), 2-term MFMA
// with chained acc, in-register cell update, bf16 h write.
template<int NT, int KS, int HK, bool WRB, bool LASTL>
__device__ __forceinline__ void step_body(
    int t, int T0, int lane,
    const short* Arh,            // act read buf
    short* Awh,                  // own act write buf (h at HK+n)
    short* Axh,                  // boundary buf (k=n), if WRB
    float* hfp,
    const short8 (&Wh)[NT][KS], const short8 (&Wl)[NT][KS],
    float (&cst)[NT])
{
    const int b = lane & 15, kg = lane >> 4;

    short8 Ah[KS];
    #pragma unroll
    for (int ks = 0; ks < KS; ++ks)
        Ah[ks] = *(const short8*)&Arh[(ks * 4 + kg) * 128 + b * 8];

    f32x4 acc[NT];
    #pragma unroll
    for (int q = 0; q < NT; ++q) acc[q] = (f32x4){0.0f, 0.0f, 0.0f, 0.0f};

    #pragma unroll
    for (int ks = 0; ks < KS; ++ks)
        #pragma unroll
        for (int q = 0; q < NT; ++q)
            acc[q] = __builtin_amdgcn_mfma_f32_16x16x32_bf16(Wh[q][ks], Ah[ks], acc[q], 0, 0, 0);
    #pragma unroll
    for (int ks = 0; ks < KS; ++ks)
        #pragma unroll
        for (int q = 0; q < NT; ++q)
            acc[q] = __builtin_amdgcn_mfma_f32_16x16x32_bf16(Wl[q][ks], Ah[ks], acc[q], 0, 0, 0);

    #pragma unroll
    for (int q = 0; q < NT; ++q) {
        int n = (T0 + q) * 4 + kg;
        if (n < 50) {
            float h = cell_upd(acc[q], cst[q]);
            unsigned short hb = f2bf(h);
            int k  = HK + n;
            Awh[(k >> 3) * 128 + b * 8 + (k & 7)] = (short)hb;
            if (WRB)
                Axh[(n >> 3) * 128 + b * 8 + (n & 7)] = (short)hb;
            if (LASTL && t == T_STEPS - 1) hfp[b * 56 + n] = h;
        }
    }
}

template<int NT, bool XST>
__device__ void role_l0(int T0, int lane, int b0, const float* __restrict__ xf,
    const float* w_ih, const float* w_hh, const float* b_ih, const float* b_hh,
    short (*A0h)[1024], short (*A1h)[2048])
{
    short8 Wh[NT][2], Wl[NT][2];
    load_wb<NT, 2, 8, 58>(T0, lane, w_ih, w_hh, b_ih, b_hh, Wh, Wl);
    float cst[NT];
    #pragma unroll
    for (int q = 0; q < NT; ++q) cst[q] = 0.0f;
    const int bb = lane & 15, kg = lane >> 4;

    for (int it = 0; it < T_STEPS + 2; ++it) {
        const bool stg = XST && (kg == 0) && (it + 1 < T_STEPS);
        float xs[8];
        if (stg) {
            const float* xr = &xf[((size_t)(b0 + bb) * T_STEPS + (it + 1)) * 8];
            *(float4*)&xs[0] = *(const float4*)xr;
            *(float4*)&xs[4] = *(const float4*)(xr + 4);
        }
        if (it < T_STEPS) {
            int cur = it & 1, nxt = cur ^ 1;
            step_body<NT, 2, 8, true, false>(it, T0, lane,
                A0h[cur], A0h[nxt], A1h[cur], nullptr, Wh, Wl, cst);
        }
        if (stg) {
            int nb = (it + 1) & 1;
            short8 hi;
            #pragma unroll
            for (int e = 0; e < 8; ++e) hi[e] = (short)f2bf(xs[e]);
            *(short8*)&A0h[nb][bb * 8] = hi;
        }
        BAR();
    }
}

// Mid-layer wave, NT=3. LASTL: L2 (skew 2, hf at t=255); else L1 (-> A2).
template<bool LASTL>
__device__ void role_mid(int T0, int lane,
    const float* w_ih, const float* w_hh, const float* b_ih, const float* b_hh,
    short (*Arh)[2048], short (*Axh)[2048], float* hfp)
{
    constexpr int SKEW = LASTL ? 2 : 1;
    short8 Wh[3][4], Wl[3][4];
    load_wb<3, 4, 50, 100>(T0, lane, w_ih, w_hh, b_ih, b_hh, Wh, Wl);
    float cst[3] = {0.0f, 0.0f, 0.0f};

    for (int it = 0; it < T_STEPS + 2; ++it) {
        int t = it - SKEW;
        if (t >= 0 && t < T_STEPS) {
            step_body<3, 4, 50, !LASTL, LASTL>(t, T0, lane,
                Arh[t & 1], Arh[(t + 1) & 1],
                LASTL ? (short*)nullptr : Axh[t & 1],
                hfp, Wh, Wl, cst);
        }
        BAR();
    }
}

// Fused dual-orphan: L1 tile12 (t1=it-1) + L2 tile12 (t2=it-2).
__device__ void role_orphan(int lane,
    const float* w_ih1, const float* w_hh1, const float* b_ih1, const float* b_hh1,
    const float* w_ih2, const float* w_hh2, const float* b_ih2, const float* b_hh2,
    short (*A1h)[2048], short (*A2h)[2048], float* hfp)
{
    short8 W1h[1][4], W1l[1][4], W2h[1][4], W2l[1][4];
    load_wb<1, 4, 50, 100>(12, lane, w_ih1, w_hh1, b_ih1, b_hh1, W1h, W1l);
    load_wb<1, 4, 50, 100>(12, lane, w_ih2, w_hh2, b_ih2, b_hh2, W2h, W2l);
    float c1 = 0.0f, c2 = 0.0f;
    const int b = lane & 15, kg = lane >> 4;

    for (int it = 0; it < T_STEPS + 2; ++it) {
        int t1 = it - 1, t2 = it - 2;
        bool d1 = (unsigned)t1 < T_STEPS, d2 = (unsigned)t2 < T_STEPS;

        short8 A1[4], A2[4];
        #pragma unroll
        for (int ks = 0; ks < 4; ++ks) {
            int ga = (ks * 4 + kg) * 128 + b * 8;
            if (d1) A1[ks] = *(const short8*)&A1h[t1 & 1][ga];
            if (d2) A2[ks] = *(const short8*)&A2h[t2 & 1][ga];
        }

        f32x4 a1 = (f32x4){0.0f, 0.0f, 0.0f, 0.0f};
        f32x4 a2 = (f32x4){0.0f, 0.0f, 0.0f, 0.0f};
        #pragma unroll
        for (int ks = 0; ks < 4; ++ks) {
            if (d1) a1 = __builtin_amdgcn_mfma_f32_16x16x32_bf16(W1h[0][ks], A1[ks], a1, 0, 0, 0);
            if (d2) a2 = __builtin_amdgcn_mfma_f32_16x16x32_bf16(W2h[0][ks], A2[ks], a2, 0, 0, 0);
        }
        #pragma unroll
        for (int ks = 0; ks < 4; ++ks) {
            if (d1) a1 = __builtin_amdgcn_mfma_f32_16x16x32_bf16(W1l[0][ks], A1[ks], a1, 0, 0, 0);
            if (d2) a2 = __builtin_amdgcn_mfma_f32_16x16x32_bf16(W2l[0][ks], A2[ks], a2, 0, 0, 0);
        }

        const int n = 48 + kg;                     // valid kg<2
        if (d1 && kg < 2) {
            float h = cell_upd(a1, c1);
            unsigned short hb = f2bf(h);
            int k = 50 + n;
            A1h[(t1 + 1) & 1][(k >> 3) * 128 + b * 8 + (k & 7)] = (short)hb;
            A2h[t1 & 1][(n >> 3) * 128 + b * 8 + (n & 7)] = (short)hb;
        }
        if (d2 && kg < 2) {
            float h = cell_upd(a2, c2);
            unsigned short hb = f2bf(h);
            int k = 50 + n;
            A2h[(t2 + 1) & 1][(k >> 3) * 128 + b * 8 + (k & 7)] = (short)hb;
            if (t2 == T_STEPS - 1) hfp[b * 56 + n] = h;
        }
        BAR();
    }
}

__global__ __launch_bounds__(NTHR) void lstm_fused(
    const float* __restrict__ xf,
    const float* w_ih0, const float* w_hh0, const float* b_ih0, const float* b_hh0,
    const float* w_ih1, const float* w_hh1, const float* b_ih1, const float* b_hh1,
    const float* w_ih2, const float* w_hh2, const float* b_ih2, const float* b_hh2,
    const float* __restrict__ w_fc, const float* __restrict__ b_fc,
    float* __restrict__ out)
{
    __shared__ __align__(16) short A0h[2][1024];   // L0 act (K=64), bf16 hi only
    __shared__ __align__(16) short A1h[2][2048];   // L1 act (K=128)
    __shared__ __align__(16) short A2h[2][2048];   // L2 act (K=128)
    __shared__ __align__(16) float hf[16 * 56];

    const int tid  = threadIdx.x;
    const int lane = tid & 63;
    const int wid  = tid >> 6;
    const int b0   = blockIdx.x * 16;

    for (int i = tid; i < 2048; i += NTHR) ((short*)A0h)[i] = 0;
    for (int i = tid; i < 4096; i += NTHR) { ((short*)A1h)[i] = 0; ((short*)A2h)[i] = 0; }
    __syncthreads();

    // bias act columns = 1.0 (both bufs); x(0) -> A0 buf0
    if (tid < 32) {
        int buf = tid >> 4, b = tid & 15;
        A0h[buf][(58 >> 3) * 128 + b * 8 + (58 & 7)] = (short)0x3F80;
        A1h[buf][(100 >> 3) * 128 + b * 8 + (100 & 7)] = (short)0x3F80;
        A2h[buf][(100 >> 3) * 128 + b * 8 + (100 & 7)] = (short)0x3F80;
    }
    if (tid < 16) {
        int b = tid;
        #pragma unroll
        for (int j = 0; j < 8; ++j) {
            float v = xf[((size_t)(b0 + b) * T_STEPS + 0) * 8 + j];
            A0h[0][b * 8 + j] = (short)f2bf(v);
        }
    }
    __syncthreads();

    if      (wid == 0)  role_l0<5, false>(0, lane, b0, xf, w_ih0, w_hh0, b_ih0, b_hh0, A0h, A1h);
    else if (wid == 1)  role_l0<4, false>(5, lane, b0, xf, w_ih0, w_hh0, b_ih0, b_hh0, A0h, A1h);
    else if (wid == 2)  role_l0<4, true >(9, lane, b0, xf, w_ih0, w_hh0, b_ih0, b_hh0, A0h, A1h);
    else if (wid == 3)  role_mid<false>(0, lane, w_ih1, w_hh1, b_ih1, b_hh1, A1h, A2h, nullptr);
    else if (wid == 4)  role_mid<false>(3, lane, w_ih1, w_hh1, b_ih1, b_hh1, A1h, A2h, nullptr);
    else if (wid == 5)  role_mid<false>(6, lane, w_ih1, w_hh1, b_ih1, b_hh1, A1h, A2h, nullptr);
    else if (wid == 6)  role_mid<false>(9, lane, w_ih1, w_hh1, b_ih1, b_hh1, A1h, A2h, nullptr);
    else if (wid == 7)  role_mid<true >(0, lane, w_ih2, w_hh2, b_ih2, b_hh2, A2h, nullptr, hf);
    else if (wid == 8)  role_mid<true >(3, lane, w_ih2, w_hh2, b_ih2, b_hh2, A2h, nullptr, hf);
    else if (wid == 9)  role_mid<true >(6, lane, w_ih2, w_hh2, b_ih2, b_hh2, A2h, nullptr, hf);
    else if (wid == 10) role_mid<true >(9, lane, w_ih2, w_hh2, b_ih2, b_hh2, A2h, nullptr, hf);
    else                role_orphan(lane,
                            w_ih1, w_hh1, b_ih1, b_hh1,
                            w_ih2, w_hh2, b_ih2, b_hh2,
                            A1h, A2h, hf);

    __syncthreads();

    if (tid < 96) {
        int b = tid / 6, o = tid - b * 6;
        float a = b_fc[o];
        #pragma unroll
        for (int n = 0; n < 50; ++n)
            a = fmaf(w_fc[o * 50 + n], hf[b * 56 + n], a);
        out[(size_t)(b0 + b) * 6 + o] = a;
    }
}

extern "C" void kernel_launch(void* const* d_in, const int* in_sizes, int n_in,
                              void* d_out, int out_size, void* d_ws, size_t ws_size,
                              hipStream_t stream) {
    (void)in_sizes; (void)n_in; (void)d_ws; (void)ws_size; (void)out_size;

    const float* x     = (const float*)d_in[0];
    const float* w_ih0 = (const float*)d_in[1];
    const float* w_hh0 = (const float*)d_in[2];
    const float* b_ih0 = (const float*)d_in[3];
    const float* b_hh0 = (const float*)d_in[4];
    const float* w_ih1 = (const float*)d_in[5];
    const float* w_hh1 = (const float*)d_in[6];
    const float* b_ih1 = (const float*)d_in[7];
    const float* b_hh1 = (const float*)d_in[8];
    const float* w_ih2 = (const float*)d_in[9];
    const float* w_hh2 = (const float*)d_in[10];
    const float* b_ih2 = (const float*)d_in[11];
    const float* b_hh2 = (const float*)d_in[12];
    const float* w_fc  = (const float*)d_in[13];
    const float* b_fc  = (const float*)d_in[14];
    float* out = (float*)d_out;

    lstm_fused<<<dim3(BTOT / 16), dim3(NTHR), 0, stream>>>(
        x, w_ih0, w_hh0, b_ih0, b_hh0, w_ih1, w_hh1, b_ih1, b_hh1,
        w_ih2, w_hh2, b_ih2, b_hh2, w_fc, b_fc, out);
}